// Round 4
// baseline (800.404 us; speedup 1.0000x reference)
//
#include <hip/hip_runtime.h>

#define NB 30000
#define NC 80
#define NIMG 8
#define MAXDET 300
#define BN (NIMG * NB)
#define SCORE_T 0.05f

#define NBINS 4096
#define CAPK 4096
#define KTARGET 4000

// ---------- helpers ----------
__device__ __forceinline__ unsigned int fsort(float s) {
  unsigned int b = __float_as_uint(s);
  return (b & 0x80000000u) ? ~b : (b | 0x80000000u);
}
__device__ __forceinline__ float funsort(unsigned int u) {
  return __uint_as_float((u & 0x80000000u) ? (u ^ 0x80000000u) : ~u);
}
__device__ __forceinline__ int vbin(float s) {
  int bn = (int)(s * (float)NBINS);
  return bn < 0 ? 0 : (bn > NBINS - 1 ? NBINS - 1 : bn);
}
// exact IoU>0.5 test, matching reference float semantics (no FMA contraction)
__device__ __forceinline__ bool sup(float ay0, float ay1, float ax0, float ax1, float aa,
                                    float by0, float by1, float bx0, float bx1, float ba) {
  float ih = fmaxf(__fsub_rn(fminf(ay1, by1), fmaxf(ay0, by0)), 0.0f);
  float iw = fmaxf(__fsub_rn(fminf(ax1, bx1), fmaxf(ax0, bx0)), 0.0f);
  float inter = __fmul_rn(ih, iw);
  if (!(inter > 0.0f)) return false;
  float uni = __fsub_rn(__fadd_rn(aa, ba), inter);
  return __fdiv_rn(inter, uni) > 0.5f;
}

// ---------- kernel 1: canonicalize boxes into SoA ----------
__global__ __launch_bounds__(256) void prep_boxes(const float* __restrict__ boxes,
                                                  float* __restrict__ soa) {
  int i = blockIdx.x * 256 + threadIdx.x;
  if (i >= BN) return;
  float4 bb = reinterpret_cast<const float4*>(boxes)[i];
  float y0 = fminf(bb.x, bb.z), y1 = fmaxf(bb.x, bb.z);
  float x0 = fminf(bb.y, bb.w), x1 = fmaxf(bb.y, bb.w);
  soa[i] = y0;
  soa[BN + i] = y1;
  soa[2 * (size_t)BN + i] = x0;
  soa[3 * (size_t)BN + i] = x1;
  soa[4 * (size_t)BN + i] = __fmul_rn(__fsub_rn(y1, y0), __fsub_rn(x1, x0));
}

// ---------- kernel 2: transpose classification [B][N][C] -> [B][C][N] ----------
__global__ __launch_bounds__(256) void transpose_cls(const float* __restrict__ cls,
                                                     float* __restrict__ clsT) {
  __shared__ float tile[64][81];  // +1 pad: avoids 32-way bank conflict on write phase
  int b = blockIdx.y;
  int n0 = blockIdx.x * 64;
  int t = threadIdx.x;
  int nmax = NB - n0;
  if (nmax > 64) nmax = 64;
  const float* src = cls + ((size_t)b * NB + n0) * NC;
  for (int i = t; i < nmax * NC; i += 256) tile[i / NC][i % NC] = src[i];
  __syncthreads();
  float* dst = clsT + (size_t)b * NC * NB;
  for (int i = t; i < NC * 64; i += 256) {
    int c = i >> 6, r = i & 63;
    if (r < nmax) dst[(size_t)c * NB + n0 + r] = tile[r][c];
  }
}

// ---------- kernel 3: per-(image,class) greedy NMS ----------
__global__ __launch_bounds__(1024) void nms_kernel(const float* __restrict__ cls, int useT,
                                                   const float* __restrict__ clsT,
                                                   const float* __restrict__ soa,
                                                   float* __restrict__ selScore,
                                                   int* __restrict__ selIdx) {
  const int prob = blockIdx.x;  // b*NC + c
  const int b = prob / NC, c = prob % NC;
  const int t = threadIdx.x;
  const int wid = t >> 6;

  __shared__ unsigned int hist[NBINS];          // 16 KB
  __shared__ unsigned long long buf[CAPK];      // 32 KB
  __shared__ unsigned int suf[1024];            // 4 KB
  __shared__ float py0[MAXDET], py1[MAXDET], px0[MAXDET], px1[MAXDET], pa[MAXDET], ps[MAXDET];
  __shared__ int pidx[MAXDET];
  __shared__ unsigned long long wmask[16];
  __shared__ int ctlBeta, ctlM, ctlCnt, ctlNp;

  const float* scol;
  size_t sstr;
  if (useT) { scol = clsT + ((size_t)b * NC + c) * NB; sstr = 1; }
  else      { scol = cls + (size_t)b * NB * NC + c;    sstr = NC; }

  const float* Y0 = soa + (size_t)b * NB;
  const float* Y1 = soa + (size_t)BN + (size_t)b * NB;
  const float* X0 = soa + 2 * (size_t)BN + (size_t)b * NB;
  const float* X1 = soa + 3 * (size_t)BN + (size_t)b * NB;
  const float* AR = soa + 4 * (size_t)BN + (size_t)b * NB;

  if (t == 0) ctlNp = 0;
  unsigned long long prevmin = ~0ULL;
  bool finished = false;
  __syncthreads();

  while (!finished) {
    // ---- histogram over remaining candidates (key < prevmin, score > T) ----
    for (int i = t; i < NBINS; i += 1024) hist[i] = 0;
    __syncthreads();
    for (int n = t; n < NB; n += 1024) {
      float s = scol[(size_t)n * sstr];
      if (s > SCORE_T) {
        unsigned long long key =
            ((unsigned long long)fsort(s) << 32) | (unsigned long long)(0xFFFFFFFFu - (unsigned)n);
        if (key < prevmin) atomicAdd(&hist[vbin(s)], 1u);
      }
    }
    __syncthreads();
    // suffix scan over 1024 groups of 4 bins
    unsigned int part = hist[4 * t] + hist[4 * t + 1] + hist[4 * t + 2] + hist[4 * t + 3];
    suf[t] = part;
    __syncthreads();
    for (int d = 1; d < 1024; d <<= 1) {
      unsigned int v = (t + d < 1024) ? suf[t + d] : 0u;
      __syncthreads();
      suf[t] += v;
      __syncthreads();
    }
    unsigned int total = suf[0];
    if (total == 0) break;  // uniform: no candidates left
    if (total < (unsigned)KTARGET) {
      if (t == 0) { ctlBeta = 0; ctlM = (int)total; }
    } else {
      bool win = (suf[t] >= (unsigned)KTARGET) && (t == 1023 || suf[t + 1] < (unsigned)KTARGET);
      if (win) {
        unsigned int run = (t == 1023) ? 0u : suf[t + 1];
        int beta = 4 * t;
        unsigned int m = suf[t];
        for (int i = 3; i >= 0; --i) {
          run += hist[4 * t + i];
          if (run >= (unsigned)KTARGET) { beta = 4 * t + i; m = run; break; }
        }
        if (m > (unsigned)CAPK) {
          unsigned int m2 = m - hist[beta];
          if (m2 == 0) { ctlBeta = beta; ctlM = CAPK; }  // pathological fallback (unreachable here)
          else         { ctlBeta = beta + 1; ctlM = (int)m2; }
        } else { ctlBeta = beta; ctlM = (int)m; }
      }
    }
    if (t == 0) ctlCnt = 0;
    __syncthreads();
    const int beta = ctlBeta;
    // ---- gather keys of bins >= beta ----
    for (int n = t; n < NB; n += 1024) {
      float s = scol[(size_t)n * sstr];
      if (s > SCORE_T) {
        unsigned long long key =
            ((unsigned long long)fsort(s) << 32) | (unsigned long long)(0xFFFFFFFFu - (unsigned)n);
        if (key < prevmin && vbin(s) >= beta) {
          int pos = atomicAdd(&ctlCnt, 1);
          if (pos < CAPK) buf[pos] = key;
        }
      }
    }
    __syncthreads();
    int M = ctlCnt < CAPK ? ctlCnt : CAPK;
    // ---- bitonic sort descending (pad with 0 = smallest) ----
    int S = 2048;
    while (S < M) S <<= 1;
    for (int i = M + t; i < S; i += 1024) buf[i] = 0ULL;
    __syncthreads();
    for (int k = 2; k <= S; k <<= 1) {
      for (int j = k >> 1; j > 0; j >>= 1) {
        for (int i = t; i < S; i += 1024) {
          int ixj = i ^ j;
          if (ixj > i) {
            unsigned long long a = buf[i], bb = buf[ixj];
            if (((i & k) != 0) == (a > bb)) { buf[i] = bb; buf[ixj] = a; }
          }
        }
        __syncthreads();
      }
    }
    unsigned long long lastkey = buf[M - 1];
    bool remaining = (total > (unsigned)M);
    bool hit300 = false;
    // ---- sequential-scan NMS over sorted candidates, 1024 at a time ----
    for (int base = 0; base < M; base += 1024) {
      int pos = base + t;
      bool has = pos < M;
      float s = 0.f, cy0 = 0.f, cy1 = 0.f, cx0 = 0.f, cx1 = 0.f, ca = 0.f;
      int n = 0;
      if (has) {
        unsigned long long key = buf[pos];
        s = funsort((unsigned)(key >> 32));
        n = (int)(0xFFFFFFFFu - (unsigned)(key & 0xFFFFFFFFu));
        cy0 = Y0[n]; cy1 = Y1[n]; cx0 = X0[n]; cx1 = X1[n]; ca = AR[n];
      }
      bool alive = has;
      int np0 = ctlNp;
      if (__any(alive ? 1 : 0)) {
        for (int i = 0; i < np0; ++i) {
          if (alive && sup(py0[i], py1[i], px0[i], px1[i], pa[i], cy0, cy1, cx0, cx1, ca))
            alive = false;
        }
      }
      while (true) {
        wmask[wid] = __ballot(alive ? 1 : 0);
        __syncthreads();
        int ft = -1;
#pragma unroll
        for (int w = 0; w < 16; ++w) {
          if (ft < 0 && wmask[w] != 0ULL) ft = w * 64 + __builtin_ctzll(wmask[w]);
        }
        if (ft < 0) break;  // uniform
        if (t == ft) {
          int np = ctlNp;
          py0[np] = cy0; py1[np] = cy1; px0[np] = cx0; px1[np] = cx1;
          pa[np] = ca; ps[np] = s; pidx[np] = n;
          ctlNp = np + 1;
          alive = false;
        }
        __syncthreads();
        int np = ctlNp;
        if (alive && sup(py0[np - 1], py1[np - 1], px0[np - 1], px1[np - 1], pa[np - 1],
                         cy0, cy1, cx0, cx1, ca))
          alive = false;
        if (np >= MAXDET) { hit300 = true; break; }  // uniform
      }
      __syncthreads();
      if (hit300) break;
    }
    finished = hit300 || !remaining;
    prevmin = lastkey;
  }
  __syncthreads();
  int np = ctlNp;
  for (int j = t; j < MAXDET; j += 1024) {
    bool real = j < np;
    selScore[(size_t)prob * MAXDET + j] = real ? ps[j] : __uint_as_float(0xFF800000u);  // -inf
    selIdx[(size_t)prob * MAXDET + j] = real ? pidx[j] : NB;
  }
}

// ---------- kernel 4: per-image stable top-300 across 80*300 candidates ----------
__global__ __launch_bounds__(1024) void final_topk(const float* __restrict__ boxes,
                                                   const float* __restrict__ selScore,
                                                   const int* __restrict__ selIdx,
                                                   float* __restrict__ out) {
  const int b = blockIdx.x, t = threadIdx.x;
  __shared__ unsigned int hist[NBINS];
  __shared__ unsigned long long buf[CAPK];
  __shared__ unsigned int suf[1024];
  __shared__ int ctlBeta, ctlCnt;
  const float* S = selScore + (size_t)b * NC * MAXDET;
  const int* I = selIdx + (size_t)b * NC * MAXDET;
  const int TOT = NC * MAXDET;  // 24000

  for (int i = t; i < NBINS; i += 1024) hist[i] = 0;
  __syncthreads();
  for (int i = t; i < TOT; i += 1024) {
    float s = S[i];
    if (s > SCORE_T) atomicAdd(&hist[vbin(s)], 1u);
  }
  __syncthreads();
  unsigned int part = hist[4 * t] + hist[4 * t + 1] + hist[4 * t + 2] + hist[4 * t + 3];
  suf[t] = part;
  __syncthreads();
  for (int d = 1; d < 1024; d <<= 1) {
    unsigned int v = (t + d < 1024) ? suf[t + d] : 0u;
    __syncthreads();
    suf[t] += v;
    __syncthreads();
  }
  unsigned int total = suf[0];
  if (total < (unsigned)MAXDET) {
    if (t == 0) ctlBeta = 0;
  } else {
    bool win = (suf[t] >= (unsigned)MAXDET) && (t == 1023 || suf[t + 1] < (unsigned)MAXDET);
    if (win) {
      unsigned int run = (t == 1023) ? 0u : suf[t + 1];
      int beta = 4 * t;
      unsigned int m = suf[t];
      for (int i = 3; i >= 0; --i) {
        run += hist[4 * t + i];
        if (run >= (unsigned)MAXDET) { beta = 4 * t + i; m = run; break; }
      }
      if (m > (unsigned)CAPK) {
        unsigned int m2 = m - hist[beta];
        ctlBeta = (m2 == 0) ? beta : beta + 1;  // pathological fallback (unreachable here)
      } else ctlBeta = beta;
    }
  }
  if (t == 0) ctlCnt = 0;
  __syncthreads();
  const int beta = ctlBeta;
  for (int i = t; i < TOT; i += 1024) {
    float s = S[i];
    if (s > SCORE_T && vbin(s) >= beta) {
      int pos = atomicAdd(&ctlCnt, 1);
      if (pos < CAPK)
        buf[pos] =
            ((unsigned long long)fsort(s) << 32) | (unsigned long long)(0xFFFFFFFFu - (unsigned)i);
    }
  }
  __syncthreads();
  int M = ctlCnt < CAPK ? ctlCnt : CAPK;
  int Ssz = 1024;
  while (Ssz < M) Ssz <<= 1;
  for (int i = M + t; i < Ssz; i += 1024) buf[i] = 0ULL;
  __syncthreads();
  for (int k = 2; k <= Ssz; k <<= 1) {
    for (int j = k >> 1; j > 0; j >>= 1) {
      for (int i = t; i < Ssz; i += 1024) {
        int ixj = i ^ j;
        if (ixj > i) {
          unsigned long long a = buf[i], bb = buf[ixj];
          if (((i & k) != 0) == (a > bb)) { buf[i] = bb; buf[ixj] = a; }
        }
      }
      __syncthreads();
    }
  }
  // dummy2 = flat index TOT-1 (reference's threshold-replacement target)
  float dumS = S[TOT - 1];
  int dumN = I[TOT - 1];
  if (t < MAXDET) {
    bool real = t < M;
    float os;
    int on, oc;
    if (real) {
      unsigned long long key = buf[t];
      os = funsort((unsigned)(key >> 32));
      int flat = (int)(0xFFFFFFFFu - (unsigned)(key & 0xFFFFFFFFu));
      oc = flat / MAXDET;
      on = I[flat];
    } else {
      os = dumS;
      on = dumN;
      oc = NC - 1;
    }
    float b0, b1, b2, b3, lab;
    if (on == NB) {
      b0 = b1 = b2 = b3 = 0.f;
      lab = -1.f;
    } else {
      const float* bp = boxes + ((size_t)b * NB + on) * 4;
      b0 = bp[0]; b1 = bp[1]; b2 = bp[2]; b3 = bp[3];
      lab = (float)oc;
    }
    float* ob = out;                                   // [8][300][4]
    float* osp = out + (size_t)NIMG * MAXDET * 4;      // [8][300]
    float* olb = osp + (size_t)NIMG * MAXDET;          // [8][300]
    size_t r = (size_t)b * MAXDET + t;
    ob[r * 4 + 0] = b0; ob[r * 4 + 1] = b1; ob[r * 4 + 2] = b2; ob[r * 4 + 3] = b3;
    osp[r] = os;
    olb[r] = lab;
  }
}

extern "C" void kernel_launch(void* const* d_in, const int* in_sizes, int n_in, void* d_out,
                              int out_size, void* d_ws, size_t ws_size, hipStream_t stream) {
  (void)in_sizes; (void)n_in; (void)out_size;
  const float* boxes = (const float*)d_in[0];
  const float* cls = (const float*)d_in[1];

  float* ws = (float*)d_ws;
  float* soa = ws;                                          // 5*BN floats
  float* selScore = ws + 5 * (size_t)BN;                    // NIMG*NC*MAXDET floats
  int* selIdx = (int*)(ws + 5 * (size_t)BN + (size_t)NIMG * NC * MAXDET);
  float* clsT = ws + 5 * (size_t)BN + 2 * (size_t)NIMG * NC * MAXDET;
  size_t need =
      (5 * (size_t)BN + 2 * (size_t)NIMG * NC * MAXDET + (size_t)NIMG * NC * NB) * sizeof(float);
  int useT = (ws_size >= need) ? 1 : 0;

  prep_boxes<<<(BN + 255) / 256, 256, 0, stream>>>(boxes, soa);
  if (useT) transpose_cls<<<dim3((NB + 63) / 64, NIMG), 256, 0, stream>>>(cls, clsT);
  nms_kernel<<<NIMG * NC, 1024, 0, stream>>>(cls, useT, clsT, soa, selScore, selIdx);
  final_topk<<<NIMG, 1024, 0, stream>>>(boxes, selScore, selIdx, (float*)d_out);
}

// Round 5
// 413.816 us; speedup vs baseline: 1.9342x; 1.9342x over previous
//
#include <hip/hip_runtime.h>

#define NB 30000
#define NC 80
#define NIMG 8
#define MAXDET 300
#define BN (NIMG * NB)
#define SCORE_T 0.05f

#define NBINS 4096

// nms_kernel parameters
#define NTHR 512
#define CAPK 512            // gather capacity (selection math guarantees <= CAPK)
#define KTARGET 448         // candidates per round; refill loop makes any value exact
#define CHUNK 256           // suppression-matrix chunk
#define NGRP (CHUNK / 64)   // 4
#define BPT (NBINS / NTHR)  // 8 bins per thread in suffix scan

// final_topk parameters
#define FTHR 1024
#define FCAP 1024
#define FBPT (NBINS / FTHR)  // 4

typedef unsigned long long u64;

// ---------- helpers ----------
__device__ __forceinline__ unsigned int fsort(float s) {
  unsigned int b = __float_as_uint(s);
  return (b & 0x80000000u) ? ~b : (b | 0x80000000u);
}
__device__ __forceinline__ float funsort(unsigned int u) {
  return __uint_as_float((u & 0x80000000u) ? (u ^ 0x80000000u) : ~u);
}
__device__ __forceinline__ int vbin(float s) {
  int bn = (int)(s * (float)NBINS);
  return bn < 0 ? 0 : (bn > NBINS - 1 ? NBINS - 1 : bn);
}
// exact IoU>0.5 test, matching reference float semantics (no FMA contraction)
__device__ __forceinline__ bool sup(float ay0, float ay1, float ax0, float ax1, float aa,
                                    float by0, float by1, float bx0, float bx1, float ba) {
  float ih = fmaxf(__fsub_rn(fminf(ay1, by1), fmaxf(ay0, by0)), 0.0f);
  float iw = fmaxf(__fsub_rn(fminf(ax1, bx1), fmaxf(ax0, bx0)), 0.0f);
  float inter = __fmul_rn(ih, iw);
  if (!(inter > 0.0f)) return false;
  float uni = __fsub_rn(__fadd_rn(aa, ba), inter);
  return __fdiv_rn(inter, uni) > 0.5f;
}

// ---------- kernel 1: canonicalize boxes into SoA ----------
__global__ __launch_bounds__(256) void prep_boxes(const float* __restrict__ boxes,
                                                  float* __restrict__ soa) {
  int i = blockIdx.x * 256 + threadIdx.x;
  if (i >= BN) return;
  float4 bb = reinterpret_cast<const float4*>(boxes)[i];
  float y0 = fminf(bb.x, bb.z), y1 = fmaxf(bb.x, bb.z);
  float x0 = fminf(bb.y, bb.w), x1 = fmaxf(bb.y, bb.w);
  soa[i] = y0;
  soa[BN + i] = y1;
  soa[2 * (size_t)BN + i] = x0;
  soa[3 * (size_t)BN + i] = x1;
  soa[4 * (size_t)BN + i] = __fmul_rn(__fsub_rn(y1, y0), __fsub_rn(x1, x0));
}

// ---------- kernel 2: transpose classification [B][N][C] -> [B][C][N] ----------
__global__ __launch_bounds__(256) void transpose_cls(const float* __restrict__ cls,
                                                     float* __restrict__ clsT) {
  __shared__ float tile[64][81];  // +1 pad: avoids bank conflicts on transposed read
  int b = blockIdx.y;
  int n0 = blockIdx.x * 64;
  int t = threadIdx.x;
  int nmax = NB - n0;
  if (nmax > 64) nmax = 64;
  const float* src = cls + ((size_t)b * NB + n0) * NC;
  for (int i = t; i < nmax * NC; i += 256) tile[i / NC][i % NC] = src[i];
  __syncthreads();
  float* dst = clsT + (size_t)b * NC * NB;
  for (int i = t; i < NC * 64; i += 256) {
    int c = i >> 6, r = i & 63;
    if (r < nmax) dst[(size_t)c * NB + n0 + r] = tile[r][c];
  }
}

// ---------- kernel 3: per-(image,class) greedy NMS ----------
// Structure per refill round: histogram -> beta cut -> gather -> rank sort ->
// per-CHUNK {load, pre-check vs picks, triangular IoU bitmask matrix,
// single-wave greedy resolution via ballot-leader}. Exactness guaranteed by
// the key-prefix property of the beta cut + refill on prevmin.
__global__ __launch_bounds__(NTHR, 6) void nms_kernel(const float* __restrict__ cls, int useT,
                                                      const float* __restrict__ clsT,
                                                      const float* __restrict__ soa,
                                                      float* __restrict__ selScore,
                                                      int* __restrict__ selIdx) {
  // XCD-swizzle: 640 = 8 XCDs x 80 blocks; each XCD owns one image's 80 classes
  const int orig = blockIdx.x;
  const int prob = (orig % 8) * (NIMG * NC / 8) + orig / 8;
  const int b = prob / NC, c = prob % NC;
  const int t = threadIdx.x;
  const int lane = t & 63;
  const int wid = t >> 6;

  __shared__ u64 buf[CAPK];  // 4 KB, persistent within a round
  __shared__ float py0[MAXDET], py1[MAXDET], px0[MAXDET], px1[MAXDET], pa[MAXDET], ps[MAXDET];
  __shared__ int pidx[MAXDET];  // picks: 8.4 KB, persistent
  __shared__ u64 aliveLDS[NGRP];
  __shared__ int ctlBeta, ctlCnt, ctlNp;
  // phase-aliased pool: phase1 = hist(16K)+suf(2K); phase2 = chunk arrays(7K)+colT(8K)
  __shared__ __align__(16) unsigned char pool[18432];

  unsigned int* hist = (unsigned int*)pool;           // 16 KB
  unsigned int* suf = (unsigned int*)(pool + 16384);  // 2 KB
  float* cy0 = (float*)pool;
  float* cy1 = (float*)(pool + 1024);
  float* cx0 = (float*)(pool + 2048);
  float* cx1 = (float*)(pool + 3072);
  float* car = (float*)(pool + 4096);
  float* csc = (float*)(pool + 5120);
  int* cn = (int*)(pool + 6144);
  u64* colT = (u64*)(pool + 7168);  // [NGRP][CHUNK] transposed column masks, 8 KB

  const float* scol;
  int sstr;
  if (useT) { scol = clsT + ((size_t)b * NC + c) * NB; sstr = 1; }
  else      { scol = cls + (size_t)b * NB * NC + c;    sstr = NC; }

  const float* Y0 = soa + (size_t)b * NB;
  const float* Y1 = soa + (size_t)BN + (size_t)b * NB;
  const float* X0 = soa + 2 * (size_t)BN + (size_t)b * NB;
  const float* X1 = soa + 3 * (size_t)BN + (size_t)b * NB;
  const float* AR = soa + 4 * (size_t)BN + (size_t)b * NB;

  if (t == 0) ctlNp = 0;
  u64 prevmin = ~0ULL;
  bool finished = false;
  __syncthreads();

  while (!finished) {
    // ---- histogram over remaining candidates (key < prevmin, score > T) ----
    for (int i = t; i < NBINS; i += NTHR) hist[i] = 0;
    __syncthreads();
    if (sstr == 1) {
      const float4* sc4 = reinterpret_cast<const float4*>(scol);
      for (int q = t; q < NB / 4; q += NTHR) {
        float4 v = sc4[q];
        float ss[4] = {v.x, v.y, v.z, v.w};
#pragma unroll
        for (int j = 0; j < 4; ++j) {
          float s = ss[j];
          if (s > SCORE_T) {
            u64 key = ((u64)fsort(s) << 32) | (u64)(0xFFFFFFFFu - (unsigned)(4 * q + j));
            if (key < prevmin) atomicAdd(&hist[vbin(s)], 1u);
          }
        }
      }
    } else {
      for (int n = t; n < NB; n += NTHR) {
        float s = scol[(size_t)n * sstr];
        if (s > SCORE_T) {
          u64 key = ((u64)fsort(s) << 32) | (u64)(0xFFFFFFFFu - (unsigned)n);
          if (key < prevmin) atomicAdd(&hist[vbin(s)], 1u);
        }
      }
    }
    __syncthreads();
    // ---- suffix scan: BPT bins per thread ----
    unsigned int part = 0;
#pragma unroll
    for (int i = 0; i < BPT; ++i) part += hist[BPT * t + i];
    suf[t] = part;
    __syncthreads();
    for (int d = 1; d < NTHR; d <<= 1) {
      unsigned int v = (t + d < NTHR) ? suf[t + d] : 0u;
      __syncthreads();
      suf[t] += v;
      __syncthreads();
    }
    unsigned int total = suf[0];
    if (total == 0) break;  // uniform: nothing above threshold left
    if (total < (unsigned)KTARGET) {
      if (t == 0) ctlBeta = 0;
    } else {
      bool win = (suf[t] >= (unsigned)KTARGET) && (t == NTHR - 1 || suf[t + 1] < (unsigned)KTARGET);
      if (win) {
        unsigned int run = (t == NTHR - 1) ? 0u : suf[t + 1];
        int beta = BPT * t;
        unsigned int m = suf[t];
        for (int i = BPT - 1; i >= 0; --i) {
          run += hist[BPT * t + i];
          if (run >= (unsigned)KTARGET) { beta = BPT * t + i; m = run; break; }
        }
        // if the boundary bin overflows CAPK, cut above it (suffix(beta+1) < KTARGET <= CAPK)
        ctlBeta = (m > (unsigned)CAPK) ? beta + 1 : beta;
      }
    }
    if (t == 0) ctlCnt = 0;
    __syncthreads();
    const int beta = ctlBeta;
    // ---- gather keys of bins >= beta ----
    if (sstr == 1) {
      const float4* sc4 = reinterpret_cast<const float4*>(scol);
      for (int q = t; q < NB / 4; q += NTHR) {
        float4 v = sc4[q];
        float ss[4] = {v.x, v.y, v.z, v.w};
#pragma unroll
        for (int j = 0; j < 4; ++j) {
          float s = ss[j];
          if (s > SCORE_T && vbin(s) >= beta) {
            u64 key = ((u64)fsort(s) << 32) | (u64)(0xFFFFFFFFu - (unsigned)(4 * q + j));
            if (key < prevmin) {
              int pos = atomicAdd(&ctlCnt, 1);
              if (pos < CAPK) buf[pos] = key;
            }
          }
        }
      }
    } else {
      for (int n = t; n < NB; n += NTHR) {
        float s = scol[(size_t)n * sstr];
        if (s > SCORE_T && vbin(s) >= beta) {
          u64 key = ((u64)fsort(s) << 32) | (u64)(0xFFFFFFFFu - (unsigned)n);
          if (key < prevmin) {
            int pos = atomicAdd(&ctlCnt, 1);
            if (pos < CAPK) buf[pos] = key;
          }
        }
      }
    }
    __syncthreads();
    int M = ctlCnt < CAPK ? ctlCnt : CAPK;
    // ---- rank sort (keys unique), descending: 2 barriers ----
    u64 mykey = 0ULL;
    int rank = 0;
    if (t < M) {
      mykey = buf[t];
      for (int i = 0; i < M; ++i) rank += (buf[i] > mykey) ? 1 : 0;
    }
    __syncthreads();
    if (t < M) buf[rank] = mykey;
    __syncthreads();
    u64 lastkey = buf[M - 1];
    bool remaining = total > (unsigned)M;
    bool hit300 = false;

    // ---- chunked suppression-matrix greedy resolution ----
    for (int base = 0; base < M; base += CHUNK) {
      int C = M - base;
      if (C > CHUNK) C = CHUNK;
      bool has = t < C;
      float ry0 = 0.f, ry1 = 0.f, rx0 = 0.f, rx1 = 0.f, rar = 0.f, rsc = 0.f;
      int rn = 0;
      if (has) {
        u64 key = buf[base + t];
        rsc = funsort((unsigned)(key >> 32));
        rn = (int)(0xFFFFFFFFu - (unsigned)(key & 0xFFFFFFFFu));
        ry0 = Y0[rn]; ry1 = Y1[rn]; rx0 = X0[rn]; rx1 = X1[rn]; rar = AR[rn];
        cy0[t] = ry0; cy1[t] = ry1; cx0[t] = rx0; cx1[t] = rx1;
        car[t] = rar; csc[t] = rsc; cn[t] = rn;
      }
      // pre-check against already-kept picks (earlier chunks / rounds)
      int np0 = ctlNp;
      bool alive = has;
      for (int i = 0; i < np0; ++i) {
        if (alive && sup(py0[i], py1[i], px0[i], px1[i], pa[i], ry0, ry1, rx0, rx1, rar))
          alive = false;
      }
      u64 ab = __ballot(alive ? 1 : 0);
      if (lane == 0 && wid < NGRP) aliveLDS[wid] = ab;
      __syncthreads();  // chunk arrays + alive masks visible
      // triangular IoU bitmask: thread t holds column t (bits i < t that suppress t)
      if (has) {
        u64 cw[NGRP] = {0};
        for (int i = 0; i < t; ++i) {
          if (sup(cy0[i], cy1[i], cx0[i], cx1[i], car[i], ry0, ry1, rx0, rx1, rar))
            cw[i >> 6] |= 1ULL << (i & 63);
        }
#pragma unroll
        for (int w = 0; w < NGRP; ++w) colT[w * CHUNK + t] = cw[w];
      }
      __syncthreads();
      // single-wave greedy resolution: zero block barriers inside
      if (wid == 0) {
        u64 keptAll[NGRP];
#pragma unroll
        for (int g = 0; g < NGRP; ++g) keptAll[g] = 0ULL;
        int np = ctlNp;
        for (int g = 0; g * 64 < C && np < MAXDET; ++g) {
          int myc = g * 64 + lane;
          bool valid = myc < C;
          u64 col[NGRP];
#pragma unroll
          for (int w = 0; w < NGRP; ++w) col[w] = valid ? colT[w * CHUNK + myc] : 0ULL;
          bool av = valid && ((aliveLDS[g] >> lane) & 1ULL);
          u64 accs = 0;
          for (int gg = 0; gg < g; ++gg) accs |= col[gg] & keptAll[gg];
          av = av && (accs == 0ULL);
          u64 wme = col[g];
          u64 rem = __ballot(av ? 1 : 0);
          u64 keptw = 0;
          while (rem) {
            if (np + __popcll(keptw) >= MAXDET) break;
            int l = __builtin_ctzll(rem);  // ascending index = greedy order
            keptw |= 1ULL << l;
            rem &= ~(1ULL << l);
            u64 supb = __ballot(((wme >> l) & 1ULL) ? 1 : 0);
            rem &= ~supb;
          }
          keptAll[g] = keptw;
          if ((keptw >> lane) & 1ULL) {
            int slot = np + __popcll(keptw & ((1ULL << lane) - 1ULL));
            py0[slot] = cy0[myc]; py1[slot] = cy1[myc];
            px0[slot] = cx0[myc]; px1[slot] = cx1[myc];
            pa[slot] = car[myc];  ps[slot] = csc[myc];
            pidx[slot] = cn[myc];
          }
          np += __popcll(keptw);
        }
        if (lane == 0) ctlNp = np;
      }
      __syncthreads();
      if (ctlNp >= MAXDET) { hit300 = true; break; }
    }
    finished = hit300 || !remaining;
    prevmin = lastkey;
  }
  __syncthreads();
  int np = ctlNp;
  for (int j = t; j < MAXDET; j += NTHR) {
    bool real = j < np;
    selScore[(size_t)prob * MAXDET + j] = real ? ps[j] : __uint_as_float(0xFF800000u);  // -inf
    selIdx[(size_t)prob * MAXDET + j] = real ? pidx[j] : NB;
  }
}

// ---------- kernel 4: per-image stable top-300 across 80*300 candidates ----------
__global__ __launch_bounds__(FTHR) void final_topk(const float* __restrict__ boxes,
                                                   const float* __restrict__ selScore,
                                                   const int* __restrict__ selIdx,
                                                   float* __restrict__ out) {
  const int b = blockIdx.x, t = threadIdx.x;
  __shared__ unsigned int hist[NBINS];
  __shared__ u64 buf[FCAP];
  __shared__ unsigned int suf[FTHR];
  __shared__ int ctlBeta, ctlCnt;
  const float* S = selScore + (size_t)b * NC * MAXDET;
  const int* I = selIdx + (size_t)b * NC * MAXDET;
  const int TOT = NC * MAXDET;  // 24000

  for (int i = t; i < NBINS; i += FTHR) hist[i] = 0;
  __syncthreads();
  for (int i = t; i < TOT; i += FTHR) {
    float s = S[i];
    if (s > SCORE_T) atomicAdd(&hist[vbin(s)], 1u);
  }
  __syncthreads();
  unsigned int part = 0;
#pragma unroll
  for (int i = 0; i < FBPT; ++i) part += hist[FBPT * t + i];
  suf[t] = part;
  __syncthreads();
  for (int d = 1; d < FTHR; d <<= 1) {
    unsigned int v = (t + d < FTHR) ? suf[t + d] : 0u;
    __syncthreads();
    suf[t] += v;
    __syncthreads();
  }
  unsigned int total = suf[0];
  if (total < (unsigned)MAXDET) {
    if (t == 0) ctlBeta = 0;
  } else {
    bool win = (suf[t] >= (unsigned)MAXDET) && (t == FTHR - 1 || suf[t + 1] < (unsigned)MAXDET);
    if (win) {
      unsigned int run = (t == FTHR - 1) ? 0u : suf[t + 1];
      int beta = FBPT * t;
      unsigned int m = suf[t];
      for (int i = FBPT - 1; i >= 0; --i) {
        run += hist[FBPT * t + i];
        if (run >= (unsigned)MAXDET) { beta = FBPT * t + i; m = run; break; }
      }
      ctlBeta = (m > (unsigned)FCAP) ? beta + 1 : beta;
    }
  }
  if (t == 0) ctlCnt = 0;
  __syncthreads();
  const int beta = ctlBeta;
  for (int i = t; i < TOT; i += FTHR) {
    float s = S[i];
    if (s > SCORE_T && vbin(s) >= beta) {
      int pos = atomicAdd(&ctlCnt, 1);
      if (pos < FCAP)
        buf[pos] = ((u64)fsort(s) << 32) | (u64)(0xFFFFFFFFu - (unsigned)i);
    }
  }
  __syncthreads();
  int M = ctlCnt < FCAP ? ctlCnt : FCAP;
  // rank sort (keys unique), descending
  u64 mykey = 0ULL;
  int rank = 0;
  if (t < M) {
    mykey = buf[t];
    for (int i = 0; i < M; ++i) rank += (buf[i] > mykey) ? 1 : 0;
  }
  __syncthreads();
  if (t < M) buf[rank] = mykey;
  __syncthreads();
  // dummy2 = flat index TOT-1 (reference's threshold-replacement target)
  float dumS = S[TOT - 1];
  int dumN = I[TOT - 1];
  if (t < MAXDET) {
    bool real = t < M;
    float os;
    int on, oc;
    if (real) {
      u64 key = buf[t];
      os = funsort((unsigned)(key >> 32));
      int flat = (int)(0xFFFFFFFFu - (unsigned)(key & 0xFFFFFFFFu));
      oc = flat / MAXDET;
      on = I[flat];
    } else {
      os = dumS;
      on = dumN;
      oc = NC - 1;
    }
    float b0, b1, b2, b3, lab;
    if (on == NB) {
      b0 = b1 = b2 = b3 = 0.f;
      lab = -1.f;
    } else {
      const float* bp = boxes + ((size_t)b * NB + on) * 4;
      b0 = bp[0]; b1 = bp[1]; b2 = bp[2]; b3 = bp[3];
      lab = (float)oc;
    }
    float* ob = out;                               // [8][300][4]
    float* osp = out + (size_t)NIMG * MAXDET * 4;  // [8][300]
    float* olb = osp + (size_t)NIMG * MAXDET;      // [8][300]
    size_t r = (size_t)b * MAXDET + t;
    ob[r * 4 + 0] = b0; ob[r * 4 + 1] = b1; ob[r * 4 + 2] = b2; ob[r * 4 + 3] = b3;
    osp[r] = os;
    olb[r] = lab;
  }
}

extern "C" void kernel_launch(void* const* d_in, const int* in_sizes, int n_in, void* d_out,
                              int out_size, void* d_ws, size_t ws_size, hipStream_t stream) {
  (void)in_sizes; (void)n_in; (void)out_size;
  const float* boxes = (const float*)d_in[0];
  const float* cls = (const float*)d_in[1];

  float* ws = (float*)d_ws;
  float* soa = ws;                                        // 5*BN floats
  float* selScore = ws + 5 * (size_t)BN;                  // NIMG*NC*MAXDET floats
  int* selIdx = (int*)(ws + 5 * (size_t)BN + (size_t)NIMG * NC * MAXDET);
  float* clsT = ws + 5 * (size_t)BN + 2 * (size_t)NIMG * NC * MAXDET;
  size_t need =
      (5 * (size_t)BN + 2 * (size_t)NIMG * NC * MAXDET + (size_t)NIMG * NC * NB) * sizeof(float);
  int useT = (ws_size >= need) ? 1 : 0;

  prep_boxes<<<(BN + 255) / 256, 256, 0, stream>>>(boxes, soa);
  if (useT) transpose_cls<<<dim3((NB + 63) / 64, NIMG), 256, 0, stream>>>(cls, clsT);
  nms_kernel<<<NIMG * NC, NTHR, 0, stream>>>(cls, useT, clsT, soa, selScore, selIdx);
  final_topk<<<NIMG, FTHR, 0, stream>>>(boxes, selScore, selIdx, (float*)d_out);
}